// Round 7
// baseline (86.894 us; speedup 1.0000x reference)
//
#include <hip/hip_runtime.h>
#include <hip/hip_bf16.h>
#include <math.h>

#define B_ 8192
#define P_ 24
#define Q_ 12
#define E_ 256
#define V_ 1000
#define TOK_ 36
#define NK_ 129      // knots
#define NI_ 128      // intervals
#define KT_ 8        // knots per build block
#define NKBLK_ 17    // ceil(129/8)
#define NBUILD_ (P_ * NKBLK_)        // 408
#define NEMBROW_ (Q_ * V_)           // 12000
#define NEMB_BLK_ ((NEMBROW_ + 3) / 4)  // 3000
#define NTILE_ ((B_ * TOK_) / 16)    // 18432 (16 rows per tile)
#define X0_ (-6.0f)
#define DX_ (12.0f / 128.0f)
#define INVDX_ (128.0f / 12.0f)
#define LN_EPS_ 1e-5f
#define INV_E_ (1.0f / 256.0f)

typedef float vfloat4 __attribute__((ext_vector_type(4)));

__device__ __forceinline__ float gelu_exact(float u) {
    return 0.5f * u * (1.0f + erff(u * 0.70710678118654752f));
}

__device__ __forceinline__ float wave_sum(float x) {
    #pragma unroll
    for (int m = 1; m < 64; m <<= 1) x += __shfl_xor(x, m, 64);
    return x;
}

// K1: blocks [0,408) build table T[p][k][f]; blocks [408, 408+3000) compute
// per-(q,v) emb row stats {sum, sumsq}. Independent halves overlap for TLP.
__global__ __launch_bounds__(256) void build_and_embstats(
        const float* __restrict__ W1, const float* __restrict__ b1,
        const float* __restrict__ W2, const float* __restrict__ b2,
        const float* __restrict__ emb,
        float* __restrict__ T, float* __restrict__ ES) {
    __shared__ float h[KT_][E_ + 4];

    if (blockIdx.x < NBUILD_) {
        int p = blockIdx.x / NKBLK_;
        int k0 = (blockIdx.x - p * NKBLK_) * KT_;
        int f = threadIdx.x;

        float w = W1[p * E_ + f];
        float b1v = b1[p * E_ + f];
        #pragma unroll
        for (int k = 0; k < KT_; ++k) {
            float x = X0_ + (float)(k0 + k) * DX_;
            h[k][f] = gelu_exact(fmaf(x, w, b1v));
        }
        __syncthreads();

        float acc[KT_];
        float b2v = b2[p * E_ + f];
        #pragma unroll
        for (int k = 0; k < KT_; ++k) acc[k] = b2v;

        const float* W2p = W2 + (size_t)p * E_ * E_ + f;
        for (int e = 0; e < E_; e += 4) {
            float w0 = W2p[(size_t)(e + 0) * E_];
            float w1 = W2p[(size_t)(e + 1) * E_];
            float w2v = W2p[(size_t)(e + 2) * E_];
            float w3 = W2p[(size_t)(e + 3) * E_];
            #pragma unroll
            for (int k = 0; k < KT_; ++k) {
                float4 hv = *(const float4*)&h[k][e];
                acc[k] = fmaf(hv.x, w0, acc[k]);
                acc[k] = fmaf(hv.y, w1, acc[k]);
                acc[k] = fmaf(hv.z, w2v, acc[k]);
                acc[k] = fmaf(hv.w, w3, acc[k]);
            }
        }
        #pragma unroll
        for (int k = 0; k < KT_; ++k) {
            int kk = k0 + k;
            if (kk < NK_) T[((size_t)p * NK_ + kk) * E_ + f] = acc[k];
        }
    } else {
        // emb row stats: one wave per (q,v) row
        int wv = threadIdx.x >> 6;
        int lane = threadIdx.x & 63;
        int r = (blockIdx.x - NBUILD_) * 4 + wv;
        if (r >= NEMBROW_) return;
        float4 e4 = *(const float4*)&emb[(size_t)r * E_ + lane * 4];
        float s1 = e4.x + e4.y + e4.z + e4.w;
        float s2 = e4.x * e4.x + e4.y * e4.y + e4.z * e4.z + e4.w * e4.w;
        s1 = wave_sum(s1);
        s2 = wave_sum(s2);
        if (lane == 0) { ES[r * 2] = s1; ES[r * 2 + 1] = s2; }
    }
}

// K2: per-interval stats {Sa, Sc, Saa, Scc, Sac} for each (p, i). One wave each.
__global__ __launch_bounds__(256) void interval_stats(
        const float* __restrict__ T, float* __restrict__ IS) {
    int wv = threadIdx.x >> 6;
    int lane = threadIdx.x & 63;
    int m = blockIdx.x * 4 + wv;           // p*128 + i
    if (m >= P_ * NI_) return;
    int p = m >> 7;
    int i = m & 127;
    const float* rowa = T + ((size_t)p * NK_ + i) * E_ + lane * 4;
    float4 a = *(const float4*)rowa;
    float4 c = *(const float4*)(rowa + E_);
    float sa = a.x + a.y + a.z + a.w;
    float sc = c.x + c.y + c.z + c.w;
    float saa = a.x * a.x + a.y * a.y + a.z * a.z + a.w * a.w;
    float scc = c.x * c.x + c.y * c.y + c.z * c.z + c.w * c.w;
    float sac = a.x * c.x + a.y * c.y + a.z * c.z + a.w * c.w;
    sa = wave_sum(sa); sc = wave_sum(sc);
    saa = wave_sum(saa); scc = wave_sum(scc); sac = wave_sum(sac);
    if (lane == 0) {
        float* o = IS + (size_t)m * 8;
        o[0] = sa; o[1] = sc; o[2] = saa; o[3] = scc; o[4] = sac;
        o[5] = 0.f; o[6] = 0.f; o[7] = 0.f;
    }
}

// K3: persistent streaming kernel. 16 consecutive rows per tile (4 waves x 4 rows),
// grid-stride over 18432 tiles. No cross-lane ops: LN stats come precomputed.
__global__ __launch_bounds__(256) void fuse_stream(
        const float* __restrict__ T, const float* __restrict__ IS,
        const float* __restrict__ ES,
        const float* __restrict__ x_num, const int* __restrict__ x_cat,
        const float* __restrict__ emb,
        const float* __restrict__ gamma, const float* __restrict__ beta,
        float* __restrict__ out) {
    int wv = threadIdx.x >> 6;
    int lane = threadIdx.x & 63;
    int e0 = lane * 4;
    float4 g = *(const float4*)&gamma[e0];
    float4 bt = *(const float4*)&beta[e0];

    for (int tile = blockIdx.x; tile < NTILE_; tile += gridDim.x) {
        int base = tile * 16 + wv * 4;       // first of 4 consecutive rows
        int b = base / TOK_;
        int t0 = base - b * TOK_;            // multiple of 4; group never straddles num/cat
        if (t0 < P_) {
            float4 x4 = *(const float4*)&x_num[b * P_ + t0];
            float xs[4] = {x4.x, x4.y, x4.z, x4.w};
            #pragma unroll
            for (int j = 0; j < 4; ++j) {
                float s = (xs[j] - X0_) * INVDX_;
                float fi = floorf(s);
                fi = fminf(fmaxf(fi, 0.0f), (float)(NI_ - 1));
                float t = s - fi;            // unclamped -> extrapolation (algebra exact)
                int i = (int)fi;
                int pp = t0 + j;
                const float* rowa = T + ((size_t)pp * NK_ + i) * E_ + e0;
                float4 a = *(const float4*)rowa;
                float4 c = *(const float4*)(rowa + E_);
                const float* ist = IS + ((size_t)pp * NI_ + i) * 8;
                float4 q1 = *(const float4*)ist;          // Sa, Sc, Saa, Scc
                float sac = ist[4];
                float u = 1.0f - t;
                float mean = fmaf(t, q1.y - q1.x, q1.x) * INV_E_;
                float m2 = (u * u * q1.z + 2.0f * t * u * sac + t * t * q1.w) * INV_E_;
                float rstd = rsqrtf(fmaxf(m2 - mean * mean, 0.0f) + LN_EPS_);
                vfloat4 o;
                float vx = fmaf(t, c.x - a.x, a.x);
                float vy = fmaf(t, c.y - a.y, a.y);
                float vz = fmaf(t, c.z - a.z, a.z);
                float vw = fmaf(t, c.w - a.w, a.w);
                o.x = fmaf((vx - mean) * rstd, g.x, bt.x);
                o.y = fmaf((vy - mean) * rstd, g.y, bt.y);
                o.z = fmaf((vz - mean) * rstd, g.z, bt.z);
                o.w = fmaf((vw - mean) * rstd, g.w, bt.w);
                __builtin_nontemporal_store(o, (vfloat4*)&out[(size_t)(base + j) * E_ + e0]);
            }
        } else {
            int q0 = t0 - P_;
            int4 id4 = *(const int4*)&x_cat[b * Q_ + q0];
            int ids[4] = {id4.x, id4.y, id4.z, id4.w};
            #pragma unroll
            for (int j = 0; j < 4; ++j) {
                int r = (q0 + j) * V_ + ids[j];
                float4 e4 = *(const float4*)&emb[(size_t)r * E_ + e0];
                float s1 = ES[r * 2], s2 = ES[r * 2 + 1];
                float mean = s1 * INV_E_;
                float rstd = rsqrtf(fmaxf(s2 * INV_E_ - mean * mean, 0.0f) + LN_EPS_);
                vfloat4 o;
                o.x = fmaf((e4.x - mean) * rstd, g.x, bt.x);
                o.y = fmaf((e4.y - mean) * rstd, g.y, bt.y);
                o.z = fmaf((e4.z - mean) * rstd, g.z, bt.z);
                o.w = fmaf((e4.w - mean) * rstd, g.w, bt.w);
                __builtin_nontemporal_store(o, (vfloat4*)&out[(size_t)(base + j) * E_ + e0]);
            }
        }
    }
}

// Exact fallback (no workspace): direct per-row matvec with in-kernel LN.
__global__ __launch_bounds__(256) void fuse_exact(
        const float* __restrict__ x_num, const int* __restrict__ x_cat,
        const float* __restrict__ W1, const float* __restrict__ b1,
        const float* __restrict__ W2, const float* __restrict__ b2,
        const float* __restrict__ emb,
        const float* __restrict__ gamma, const float* __restrict__ beta,
        float* __restrict__ out) {
    int wv = threadIdx.x >> 6;
    int lane = threadIdx.x & 63;
    int row = blockIdx.x * 4 + wv;
    if (row >= B_ * TOK_) return;
    int b = row / TOK_;
    int t = row - b * TOK_;
    int e0 = lane * 4;
    float4 g = *(const float4*)&gamma[e0];
    float4 bt = *(const float4*)&beta[e0];
    float4 v;
    if (t < P_) {
        float x = x_num[b * P_ + t];
        float4 acc = *(const float4*)&b2[t * E_ + e0];
        for (int e = 0; e < E_; ++e) {
            float he = gelu_exact(fmaf(x, W1[t * E_ + e], b1[t * E_ + e]));
            float4 w = *(const float4*)&W2[((size_t)t * E_ + e) * E_ + e0];
            acc.x = fmaf(he, w.x, acc.x);
            acc.y = fmaf(he, w.y, acc.y);
            acc.z = fmaf(he, w.z, acc.z);
            acc.w = fmaf(he, w.w, acc.w);
        }
        v = acc;
    } else {
        int q = t - P_;
        int idx = x_cat[b * Q_ + q];
        v = *(const float4*)&emb[((size_t)q * V_ + idx) * E_ + e0];
    }
    float s1 = wave_sum(v.x + v.y + v.z + v.w);
    float mean = s1 * INV_E_;
    float dx = v.x - mean, dy = v.y - mean, dz = v.z - mean, dw = v.w - mean;
    float s2 = wave_sum(dx * dx + dy * dy + dz * dz + dw * dw);
    float rstd = rsqrtf(s2 * INV_E_ + LN_EPS_);
    vfloat4 o;
    o.x = fmaf(dx * rstd, g.x, bt.x);
    o.y = fmaf(dy * rstd, g.y, bt.y);
    o.z = fmaf(dz * rstd, g.z, bt.z);
    o.w = fmaf(dw * rstd, g.w, bt.w);
    __builtin_nontemporal_store(o, (vfloat4*)&out[(size_t)row * E_ + e0]);
}

extern "C" void kernel_launch(void* const* d_in, const int* in_sizes, int n_in,
                              void* d_out, int out_size, void* d_ws, size_t ws_size,
                              hipStream_t stream) {
    const float* x_num = (const float*)d_in[0];
    const int*   x_cat = (const int*)d_in[1];
    const float* W1    = (const float*)d_in[2];
    const float* b1    = (const float*)d_in[3];
    const float* W2    = (const float*)d_in[4];
    const float* b2    = (const float*)d_in[5];
    const float* emb   = (const float*)d_in[6];
    const float* gamma = (const float*)d_in[7];
    const float* beta  = (const float*)d_in[8];
    float* out = (float*)d_out;

    size_t tbl_floats = (size_t)P_ * NK_ * E_;                 // 3,170,304 B
    size_t is_floats  = (size_t)P_ * NI_ * 8;                  // 98,304 B
    size_t es_floats  = (size_t)NEMBROW_ * 2;                  // 96,000 B
    size_t need = (tbl_floats + is_floats + es_floats) * sizeof(float);

    if (ws_size >= need) {
        float* Tbl = (float*)d_ws;
        float* IS  = Tbl + tbl_floats;
        float* ES  = IS + is_floats;
        build_and_embstats<<<NBUILD_ + NEMB_BLK_, 256, 0, stream>>>(
            W1, b1, W2, b2, emb, Tbl, ES);
        interval_stats<<<(P_ * NI_) / 4, 256, 0, stream>>>(Tbl, IS);
        fuse_stream<<<2048, 256, 0, stream>>>(Tbl, IS, ES, x_num, x_cat, emb,
                                              gamma, beta, out);
    } else {
        int nrow_blocks = (B_ * TOK_ + 3) / 4;
        fuse_exact<<<nrow_blocks, 256, 0, stream>>>(x_num, x_cat, W1, b1, W2, b2,
                                                    emb, gamma, beta, out);
    }
}